// Round 5
// baseline (95.670 us; speedup 1.0000x reference)
//
#include <hip/hip_runtime.h>

// Live dataflow of the reference (everything else is dead code — the
// reference pools the INPUT features x, never h):
//   x[i]      = emb_weight[global_idx[i]] + acts[i] @ pe_W + pe_b      [N,256]
//   pooled[g] = sum_{batch[i]==g} x[i]                                 [64,256]
//   z         = relu(pooled @ fc1_W + fc1_b)                           [64,512]
//   out       = log_softmax(z @ fc2_W + fc2_b)                         [64,978]

#define NNODES  100000
#define NGRAPHS 64
#define DIM     256
#define HID     512
#define NOUT    978
#define NPW     16      // nodes per wave in pool_k (100000/16 = 6250 waves)

// ---------------------------------------------------------------------------
// Kernel 0: zero the pooled accumulator (replaces hipMemsetAsync, whose
// captured fillBufferAligned node measured ~40 us — >50% of total runtime).
// 16 blocks x 256 threads x float4 = 64 KB.
// ---------------------------------------------------------------------------
__global__ __launch_bounds__(256) void zero_k(float4* __restrict__ p)
{
    p[blockIdx.x * 256 + threadIdx.x] = make_float4(0.f, 0.f, 0.f, 0.f);
}

// ---------------------------------------------------------------------------
// Kernel 1: fused embed + positional-linear + segment-sum pool.
// One wave handles 16 contiguous nodes, lane owns columns [4*lane,4*lane+4).
// Fully unrolled 16-deep gather pipeline (no loop): all 16 emb float4 loads
// in flight simultaneously. pe contribution folded into the single flush via
// (sum acts, count). batch sorted -> boundary check wave-uniform; slow path
// (graph boundary inside the 16-group) hits ~1% of waves.
// ---------------------------------------------------------------------------
__global__ __launch_bounds__(256) void pool_k(
    const int* __restrict__ gidx, const float* __restrict__ acts,
    const int* __restrict__ batch, const float* __restrict__ emb,
    const float* __restrict__ peW, const float* __restrict__ peb,
    float* __restrict__ pooled)
{
    const int wave = blockIdx.x * 4 + (threadIdx.x >> 6);
    const int lane = threadIdx.x & 63;
    const int i = wave * NPW;
    if (i >= NNODES) return;

    const float4 w0 = ((const float4*)peW)[lane];          // pe_W row 0 slice
    const float4 w1 = ((const float4*)(peW + DIM))[lane];  // pe_W row 1 slice
    const float4 pb = ((const float4*)peb)[lane];          // pe_b slice

    // uniform metadata for 16 nodes (aligned: i % 16 == 0)
    const int4 b0 = *(const int4*)(batch + i);
    const int4 b1 = *(const int4*)(batch + i + 4);
    const int4 b2 = *(const int4*)(batch + i + 8);
    const int4 b3 = *(const int4*)(batch + i + 12);
    const int4 p0 = *(const int4*)(gidx + i);
    const int4 p1 = *(const int4*)(gidx + i + 4);
    const int4 p2 = *(const int4*)(gidx + i + 8);
    const int4 p3 = *(const int4*)(gidx + i + 12);
    const float4 a0 = *(const float4*)(acts + 2 * i);
    const float4 a1 = *(const float4*)(acts + 2 * i + 4);
    const float4 a2 = *(const float4*)(acts + 2 * i + 8);
    const float4 a3 = *(const float4*)(acts + 2 * i + 12);
    const float4 a4 = *(const float4*)(acts + 2 * i + 16);
    const float4 a5 = *(const float4*)(acts + 2 * i + 20);
    const float4 a6 = *(const float4*)(acts + 2 * i + 24);
    const float4 a7 = *(const float4*)(acts + 2 * i + 28);

    // 16 outstanding 1KB row gathers (compile-time-constant indices ->
    // everything stays in registers)
#define EROW(P) (*(const float4*)(emb + ((size_t)(P) << 8) + lane * 4))
    const float4 e0 = EROW(p0.x), e1 = EROW(p0.y), e2 = EROW(p0.z), e3 = EROW(p0.w);
    const float4 e4 = EROW(p1.x), e5 = EROW(p1.y), e6 = EROW(p1.z), e7 = EROW(p1.w);
    const float4 e8 = EROW(p2.x), e9 = EROW(p2.y), eA = EROW(p2.z), eB = EROW(p2.w);
    const float4 eC = EROW(p3.x), eD = EROW(p3.y), eE = EROW(p3.z), eF = EROW(p3.w);
#undef EROW

    float4 acc  = make_float4(0.f, 0.f, 0.f, 0.f);
    float2 asum = make_float2(0.f, 0.f);
    float  cnt  = 0.f;
    int cur = b0.x;

    auto flush = [&]() {
        float* p = pooled + (size_t)cur * DIM + lane * 4;
        atomicAdd(p + 0, acc.x + asum.x * w0.x + asum.y * w1.x + cnt * pb.x);
        atomicAdd(p + 1, acc.y + asum.x * w0.y + asum.y * w1.y + cnt * pb.y);
        atomicAdd(p + 2, acc.z + asum.x * w0.z + asum.y * w1.z + cnt * pb.z);
        atomicAdd(p + 3, acc.w + asum.x * w0.w + asum.y * w1.w + cnt * pb.w);
        acc = make_float4(0.f, 0.f, 0.f, 0.f);
        asum = make_float2(0.f, 0.f);
        cnt = 0.f;
    };

    if (b3.w == cur) {
        // fast path: all 16 nodes in one graph (sorted batch)
        acc.x = (((e0.x + e1.x) + (e2.x + e3.x)) + ((e4.x + e5.x) + (e6.x + e7.x)))
              + (((e8.x + e9.x) + (eA.x + eB.x)) + ((eC.x + eD.x) + (eE.x + eF.x)));
        acc.y = (((e0.y + e1.y) + (e2.y + e3.y)) + ((e4.y + e5.y) + (e6.y + e7.y)))
              + (((e8.y + e9.y) + (eA.y + eB.y)) + ((eC.y + eD.y) + (eE.y + eF.y)));
        acc.z = (((e0.z + e1.z) + (e2.z + e3.z)) + ((e4.z + e5.z) + (e6.z + e7.z)))
              + (((e8.z + e9.z) + (eA.z + eB.z)) + ((eC.z + eD.z) + (eE.z + eF.z)));
        acc.w = (((e0.w + e1.w) + (e2.w + e3.w)) + ((e4.w + e5.w) + (e6.w + e7.w)))
              + (((e8.w + e9.w) + (eA.w + eB.w)) + ((eC.w + eD.w) + (eE.w + eF.w)));
        asum.x = ((a0.x + a0.z) + (a1.x + a1.z)) + ((a2.x + a2.z) + (a3.x + a3.z))
               + ((a4.x + a4.z) + (a5.x + a5.z)) + ((a6.x + a6.z) + (a7.x + a7.z));
        asum.y = ((a0.y + a0.w) + (a1.y + a1.w)) + ((a2.y + a2.w) + (a3.y + a3.w))
               + ((a4.y + a4.w) + (a5.y + a5.w)) + ((a6.y + a6.w) + (a7.y + a7.w));
        cnt = 16.f;
        flush();
    } else {
        // graph boundary inside this 16-group (rare, wave-uniform)
#define NODE(B, E, AX, AY) do {                                   \
        if ((B) != cur) { flush(); cur = (B); }                   \
        acc.x += (E).x; acc.y += (E).y;                           \
        acc.z += (E).z; acc.w += (E).w;                           \
        asum.x += (AX); asum.y += (AY); cnt += 1.f; } while (0)
        NODE(b0.x, e0, a0.x, a0.y);
        NODE(b0.y, e1, a0.z, a0.w);
        NODE(b0.z, e2, a1.x, a1.y);
        NODE(b0.w, e3, a1.z, a1.w);
        NODE(b1.x, e4, a2.x, a2.y);
        NODE(b1.y, e5, a2.z, a2.w);
        NODE(b1.z, e6, a3.x, a3.y);
        NODE(b1.w, e7, a3.z, a3.w);
        NODE(b2.x, e8, a4.x, a4.y);
        NODE(b2.y, e9, a4.z, a4.w);
        NODE(b2.z, eA, a5.x, a5.y);
        NODE(b2.w, eB, a5.z, a5.w);
        NODE(b3.x, eC, a6.x, a6.y);
        NODE(b3.y, eD, a6.z, a6.w);
        NODE(b3.z, eE, a7.x, a7.y);
        NODE(b3.w, eF, a7.z, a7.w);
#undef NODE
        flush();
    }
}

// ---------------------------------------------------------------------------
// Kernel 2: z = relu(pooled @ fc1_W + fc1_b).  Grid (2 col-tiles, 64 graphs),
// block 256.  pooled row in LDS (float4 broadcast reads), W coalesced.
// ---------------------------------------------------------------------------
__global__ __launch_bounds__(256) void fc1_k(
    const float* __restrict__ pooled, const float* __restrict__ W,
    const float* __restrict__ bias, float* __restrict__ z)
{
    __shared__ float xs[DIM];
    const int g = blockIdx.y;
    const int j = blockIdx.x * 256 + threadIdx.x;
    xs[threadIdx.x] = pooled[g * DIM + threadIdx.x];
    __syncthreads();

    float acc = bias[j];
#pragma unroll 4
    for (int d = 0; d < DIM; d += 4) {
        const float4 x4 = *(const float4*)(xs + d);
        acc = fmaf(x4.x, W[(d + 0) * HID + j], acc);
        acc = fmaf(x4.y, W[(d + 1) * HID + j], acc);
        acc = fmaf(x4.z, W[(d + 2) * HID + j], acc);
        acc = fmaf(x4.w, W[(d + 3) * HID + j], acc);
    }
    z[g * HID + j] = fmaxf(acc, 0.f);
}

// ---------------------------------------------------------------------------
// Kernel 3a: logits = z @ fc2_W + fc2_b into d_out.  Grid (4 col-tiles,
// 16 graph-quads), block 256: each W column load feeds FOUR graphs' FMAs
// (quarters L2 W traffic, 16 FMAs per 4 loads).
// ---------------------------------------------------------------------------
__global__ __launch_bounds__(256) void fc2_k(
    const float* __restrict__ z, const float* __restrict__ W,
    const float* __restrict__ bias, float* __restrict__ out)
{
    __shared__ float zs[4 * HID];
    const int g0 = blockIdx.y * 4;
    const int j = blockIdx.x * 256 + threadIdx.x;
#pragma unroll
    for (int k = 0; k < 8; ++k) {
        const int idx = threadIdx.x + k * 256;        // 0..2047
        zs[idx] = z[g0 * HID + idx];                  // rows g0..g0+3
    }
    __syncthreads();
    if (j >= NOUT) return;

    float acc0 = bias[j], acc1 = acc0, acc2 = acc0, acc3 = acc0;
#pragma unroll 2
    for (int d = 0; d < HID; d += 4) {
        const float4 za = *(const float4*)(zs + d);
        const float4 zb = *(const float4*)(zs + HID + d);
        const float4 zc = *(const float4*)(zs + 2 * HID + d);
        const float4 zd = *(const float4*)(zs + 3 * HID + d);
        const float wa = W[(d + 0) * NOUT + j];
        const float wb = W[(d + 1) * NOUT + j];
        const float wc = W[(d + 2) * NOUT + j];
        const float wd = W[(d + 3) * NOUT + j];
        acc0 = fmaf(za.x, wa, acc0); acc1 = fmaf(zb.x, wa, acc1);
        acc2 = fmaf(zc.x, wa, acc2); acc3 = fmaf(zd.x, wa, acc3);
        acc0 = fmaf(za.y, wb, acc0); acc1 = fmaf(zb.y, wb, acc1);
        acc2 = fmaf(zc.y, wb, acc2); acc3 = fmaf(zd.y, wb, acc3);
        acc0 = fmaf(za.z, wc, acc0); acc1 = fmaf(zb.z, wc, acc1);
        acc2 = fmaf(zc.z, wc, acc2); acc3 = fmaf(zd.z, wc, acc3);
        acc0 = fmaf(za.w, wd, acc0); acc1 = fmaf(zb.w, wd, acc1);
        acc2 = fmaf(zc.w, wd, acc2); acc3 = fmaf(zd.w, wd, acc3);
    }
    out[(size_t)(g0 + 0) * NOUT + j] = acc0;
    out[(size_t)(g0 + 1) * NOUT + j] = acc1;
    out[(size_t)(g0 + 2) * NOUT + j] = acc2;
    out[(size_t)(g0 + 3) * NOUT + j] = acc3;
}

// ---------------------------------------------------------------------------
// Kernel 3b: in-place row log-softmax.  One block (4 waves) per graph row.
// ---------------------------------------------------------------------------
__global__ __launch_bounds__(256) void lsm_k(float* __restrict__ out)
{
    __shared__ float red[8];
    const int g = blockIdx.x;
    float* row = out + (size_t)g * NOUT;
    const int tid  = threadIdx.x;
    const int wid  = tid >> 6;
    const int lane = tid & 63;

    float v[4];
    float m = -INFINITY;
#pragma unroll
    for (int k = 0; k < 4; ++k) {
        const int j = tid + k * 256;
        v[k] = (j < NOUT) ? row[j] : -INFINITY;
        m = fmaxf(m, v[k]);
    }
#pragma unroll
    for (int off = 32; off > 0; off >>= 1) m = fmaxf(m, __shfl_xor(m, off));
    if (lane == 0) red[wid] = m;
    __syncthreads();
    m = fmaxf(fmaxf(red[0], red[1]), fmaxf(red[2], red[3]));

    float s = 0.f;
#pragma unroll
    for (int k = 0; k < 4; ++k) {
        const int j = tid + k * 256;
        if (j < NOUT) s += expf(v[k] - m);
    }
#pragma unroll
    for (int off = 32; off > 0; off >>= 1) s += __shfl_xor(s, off);
    if (lane == 0) red[4 + wid] = s;
    __syncthreads();
    s = red[4] + red[5] + red[6] + red[7];

    const float lse = m + logf(s);
#pragma unroll
    for (int k = 0; k < 4; ++k) {
        const int j = tid + k * 256;
        if (j < NOUT) row[j] = v[k] - lse;
    }
}

// ---------------------------------------------------------------------------
extern "C" void kernel_launch(void* const* d_in, const int* in_sizes, int n_in,
                              void* d_out, int out_size, void* d_ws, size_t ws_size,
                              hipStream_t stream)
{
    // setup_inputs() dict order
    const int*   gidx  = (const int*)  d_in[0];   // global_idx  [N]
    const float* acts  = (const float*)d_in[1];   // acts        [N,2]
    const int*   batch = (const int*)  d_in[4];   // batch       [N] (sorted)
    const float* emb   = (const float*)d_in[5];   // emb_weight  [20000,256]
    const float* peW   = (const float*)d_in[6];   // pe_W        [2,256]
    const float* peb   = (const float*)d_in[7];   // pe_b        [256]
    const float* fc1W  = (const float*)d_in[19];  // fc1_W       [256,512]
    const float* fc1b  = (const float*)d_in[20];  // fc1_b       [512]
    const float* fc2W  = (const float*)d_in[21];  // fc2_W       [512,978]
    const float* fc2b  = (const float*)d_in[22];  // fc2_b       [978]
    // d_in[2,3,8..18] (edge_index, sign, cg_*, gat_*, bn_*, prelu) are dead
    // code w.r.t. the reference output (it pools x, not h).

    float* pooled = (float*)d_ws;                 // 64*256 f32 = 64 KB
    float* z      = pooled + NGRAPHS * DIM;       // 64*512 f32 = 128 KB

    // pooled is accumulated with atomics -> zero it with our own kernel
    // (captured hipMemsetAsync fill node measured ~40 us!)
    zero_k<<<16, 256, 0, stream>>>((float4*)pooled);

    const int waves  = (NNODES + NPW - 1) / NPW;  // 6250
    const int blocks = (waves + 3) / 4;           // 1563
    pool_k<<<blocks, 256, 0, stream>>>(gidx, acts, batch, emb, peW, peb, pooled);
    fc1_k<<<dim3(2, NGRAPHS), 256, 0, stream>>>(pooled, fc1W, fc1b, z);
    fc2_k<<<dim3(4, NGRAPHS / 4), 256, 0, stream>>>(z, fc2W, fc2b, (float*)d_out);
    lsm_k<<<NGRAPHS, 256, 0, stream>>>((float*)d_out);
}

// Round 6
// 63.805 us; speedup vs baseline: 1.4994x; 1.4994x over previous
//
#include <hip/hip_runtime.h>

// Live dataflow of the reference (everything else is dead code — the
// reference pools the INPUT features x, never h):
//   x[i]      = emb_weight[global_idx[i]] + acts[i] @ pe_W + pe_b      [N,256]
//   pooled[g] = sum_{batch[i]==g} x[i]                                 [64,256]
//   z         = relu(pooled @ fc1_W + fc1_b)                           [64,512]
//   out       = log_softmax(z @ fc2_W + fc2_b)                         [64,978]
//
// R5 post-mortem: pool time ∝ flush-atomic count (atomicAdd write-through =
// 16 B HBM transaction each; 1.6M of them over a 64KB region = the floor),
// and a ~40 µs replay-startup tax is billed to the FIRST graph node. So:
// no atomics, no zero kernel — deterministic partial sums + plain stores.

#define NNODES  100000
#define NGRAPHS 64
#define DIM     256
#define HID     512
#define NOUT    978
#define SUBS    4        // sub-blocks per graph; grid = 64*4 = 256 blocks
#define CHUNKS  16       // chunks per graph = SUBS * 4 waves

// ---------------------------------------------------------------------------
// Kernel 1: fused embed + pe-linear + segment-sum, atomic-free.
// Block b = (graph g = b/4, quarter s = b%4). The block finds its node range
// [lo,hi) with an inline dual binary search over the sorted batch array
// (wave-uniform, ~17 L2-resident dependent loads). Each of the 4 waves sums
// a contiguous ~len/16 chunk of rows (groups of 8 -> 24 outstanding loads),
// folds the pe term in (sum-of-acts trick), LDS-reduces across the 4 waves,
// and writes ONE partials row per block with plain stores.
// Load-balanced by construction (multinomial graph sizes: 1562 ± 2.5%).
// ---------------------------------------------------------------------------
__global__ __launch_bounds__(256) void pool_k(
    const int* __restrict__ gidx, const float* __restrict__ acts,
    const int* __restrict__ batch, const float* __restrict__ emb,
    const float* __restrict__ peW, const float* __restrict__ peb,
    float* __restrict__ partials)
{
    const int b    = blockIdx.x;
    const int g    = b >> 2;
    const int s    = b & 3;
    const int w    = threadIdx.x >> 6;
    const int lane = threadIdx.x & 63;

    // dual lower_bound: lo = first i with batch[i] >= g, hi = ... >= g+1.
    // Two independent chains interleaved for ILP; 2^17 > 100000.
    int l0 = 0, r0 = NNODES, l1 = 0, r1 = NNODES;
#pragma unroll
    for (int it = 0; it < 17; ++it) {
        if (l0 < r0) { const int m = (l0 + r0) >> 1; if (batch[m] <  g)     l0 = m + 1; else r0 = m; }
        if (l1 < r1) { const int m = (l1 + r1) >> 1; if (batch[m] <  g + 1) l1 = m + 1; else r1 = m; }
    }
    const int lo = l0, hi = l1;

    const int cw    = s * 4 + w;                  // 0..15 chunk id within graph
    const int chunk = (hi - lo + CHUNKS - 1) >> 4;
    int       i     = lo + cw * chunk;
    const int iend  = min(i + chunk, hi);

    const float4 w0 = ((const float4*)peW)[lane];          // pe_W row 0 slice
    const float4 w1 = ((const float4*)(peW + DIM))[lane];  // pe_W row 1 slice
    const float4 pb = ((const float4*)peb)[lane];          // pe_b slice

    float4 acc = make_float4(0.f, 0.f, 0.f, 0.f);
    float  ax = 0.f, ay = 0.f, cnt = 0.f;

#define EROW(P) (*(const float4*)(emb + ((size_t)(P) << 8) + lane * 4))
    for (; i + 8 <= iend; i += 8) {
        // 8 independent index loads + 8 acts loads + 8 row gathers in flight
        const int j0 = gidx[i + 0], j1 = gidx[i + 1], j2 = gidx[i + 2], j3 = gidx[i + 3];
        const int j4 = gidx[i + 4], j5 = gidx[i + 5], j6 = gidx[i + 6], j7 = gidx[i + 7];
        const float2 a0 = ((const float2*)acts)[i + 0], a1 = ((const float2*)acts)[i + 1];
        const float2 a2 = ((const float2*)acts)[i + 2], a3 = ((const float2*)acts)[i + 3];
        const float2 a4 = ((const float2*)acts)[i + 4], a5 = ((const float2*)acts)[i + 5];
        const float2 a6 = ((const float2*)acts)[i + 6], a7 = ((const float2*)acts)[i + 7];
        const float4 e0 = EROW(j0), e1 = EROW(j1), e2 = EROW(j2), e3 = EROW(j3);
        const float4 e4 = EROW(j4), e5 = EROW(j5), e6 = EROW(j6), e7 = EROW(j7);

        acc.x += ((e0.x + e1.x) + (e2.x + e3.x)) + ((e4.x + e5.x) + (e6.x + e7.x));
        acc.y += ((e0.y + e1.y) + (e2.y + e3.y)) + ((e4.y + e5.y) + (e6.y + e7.y));
        acc.z += ((e0.z + e1.z) + (e2.z + e3.z)) + ((e4.z + e5.z) + (e6.z + e7.z));
        acc.w += ((e0.w + e1.w) + (e2.w + e3.w)) + ((e4.w + e5.w) + (e6.w + e7.w));
        ax    += ((a0.x + a1.x) + (a2.x + a3.x)) + ((a4.x + a5.x) + (a6.x + a7.x));
        ay    += ((a0.y + a1.y) + (a2.y + a3.y)) + ((a4.y + a5.y) + (a6.y + a7.y));
        cnt   += 8.f;
    }
    for (; i < iend; ++i) {                       // <=7 tail rows
        const int    j = gidx[i];
        const float2 a = ((const float2*)acts)[i];
        const float4 e = EROW(j);
        acc.x += e.x; acc.y += e.y; acc.z += e.z; acc.w += e.w;
        ax += a.x; ay += a.y; cnt += 1.f;
    }
#undef EROW

    // fold pe contribution: sum_i (acts_i @ pe_W + pe_b)
    acc.x += ax * w0.x + ay * w1.x + cnt * pb.x;
    acc.y += ax * w0.y + ay * w1.y + cnt * pb.y;
    acc.z += ax * w0.z + ay * w1.z + cnt * pb.z;
    acc.w += ax * w0.w + ay * w1.w + cnt * pb.w;

    // reduce the block's 4 waves in LDS; wave 0 writes the partials row
    __shared__ float4 red[4][64];
    red[w][lane] = acc;
    __syncthreads();
    if (w == 0) {
        const float4 r0_ = red[0][lane], r1_ = red[1][lane];
        const float4 r2_ = red[2][lane], r3_ = red[3][lane];
        float4 o;
        o.x = (r0_.x + r1_.x) + (r2_.x + r3_.x);
        o.y = (r0_.y + r1_.y) + (r2_.y + r3_.y);
        o.z = (r0_.z + r1_.z) + (r2_.z + r3_.z);
        o.w = (r0_.w + r1_.w) + (r2_.w + r3_.w);
        ((float4*)(partials + (size_t)b * DIM))[lane] = o;   // plain store
    }
}

// ---------------------------------------------------------------------------
// Kernel 2: z = relu(pooled @ fc1_W + fc1_b), where pooled[g] is the sum of
// the graph's SUBS partial rows (summed here — no extra reduction kernel).
// Grid (2 col-tiles, 64 graphs), block 256.
// ---------------------------------------------------------------------------
__global__ __launch_bounds__(256) void fc1_k(
    const float* __restrict__ partials, const float* __restrict__ W,
    const float* __restrict__ bias, float* __restrict__ z)
{
    __shared__ float xs[DIM];
    const int g = blockIdx.y;
    const int j = blockIdx.x * 256 + threadIdx.x;

    float v = 0.f;
#pragma unroll
    for (int s = 0; s < SUBS; ++s)
        v += partials[(size_t)((g << 2) + s) * DIM + threadIdx.x];  // coalesced
    xs[threadIdx.x] = v;
    __syncthreads();

    float acc = bias[j];
#pragma unroll 4
    for (int d = 0; d < DIM; d += 4) {
        const float4 x4 = *(const float4*)(xs + d);
        acc = fmaf(x4.x, W[(d + 0) * HID + j], acc);
        acc = fmaf(x4.y, W[(d + 1) * HID + j], acc);
        acc = fmaf(x4.z, W[(d + 2) * HID + j], acc);
        acc = fmaf(x4.w, W[(d + 3) * HID + j], acc);
    }
    z[g * HID + j] = fmaxf(acc, 0.f);
}

// ---------------------------------------------------------------------------
// Kernel 3a: logits = z @ fc2_W + fc2_b into d_out.  Grid (4 col-tiles,
// 16 graph-quads), block 256: each W column load feeds FOUR graphs' FMAs.
// ---------------------------------------------------------------------------
__global__ __launch_bounds__(256) void fc2_k(
    const float* __restrict__ z, const float* __restrict__ W,
    const float* __restrict__ bias, float* __restrict__ out)
{
    __shared__ float zs[4 * HID];
    const int g0 = blockIdx.y * 4;
    const int j = blockIdx.x * 256 + threadIdx.x;
#pragma unroll
    for (int k = 0; k < 8; ++k) {
        const int idx = threadIdx.x + k * 256;        // 0..2047
        zs[idx] = z[g0 * HID + idx];                  // rows g0..g0+3
    }
    __syncthreads();
    if (j >= NOUT) return;

    float acc0 = bias[j], acc1 = acc0, acc2 = acc0, acc3 = acc0;
#pragma unroll 2
    for (int d = 0; d < HID; d += 4) {
        const float4 za = *(const float4*)(zs + d);
        const float4 zb = *(const float4*)(zs + HID + d);
        const float4 zc = *(const float4*)(zs + 2 * HID + d);
        const float4 zd = *(const float4*)(zs + 3 * HID + d);
        const float wa = W[(d + 0) * NOUT + j];
        const float wb = W[(d + 1) * NOUT + j];
        const float wc = W[(d + 2) * NOUT + j];
        const float wd = W[(d + 3) * NOUT + j];
        acc0 = fmaf(za.x, wa, acc0); acc1 = fmaf(zb.x, wa, acc1);
        acc2 = fmaf(zc.x, wa, acc2); acc3 = fmaf(zd.x, wa, acc3);
        acc0 = fmaf(za.y, wb, acc0); acc1 = fmaf(zb.y, wb, acc1);
        acc2 = fmaf(zc.y, wb, acc2); acc3 = fmaf(zd.y, wb, acc3);
        acc0 = fmaf(za.z, wc, acc0); acc1 = fmaf(zb.z, wc, acc1);
        acc2 = fmaf(zc.z, wc, acc2); acc3 = fmaf(zd.z, wc, acc3);
        acc0 = fmaf(za.w, wd, acc0); acc1 = fmaf(zb.w, wd, acc1);
        acc2 = fmaf(zc.w, wd, acc2); acc3 = fmaf(zd.w, wd, acc3);
    }
    out[(size_t)(g0 + 0) * NOUT + j] = acc0;
    out[(size_t)(g0 + 1) * NOUT + j] = acc1;
    out[(size_t)(g0 + 2) * NOUT + j] = acc2;
    out[(size_t)(g0 + 3) * NOUT + j] = acc3;
}

// ---------------------------------------------------------------------------
// Kernel 3b: in-place row log-softmax.  One block (4 waves) per graph row.
// ---------------------------------------------------------------------------
__global__ __launch_bounds__(256) void lsm_k(float* __restrict__ out)
{
    __shared__ float red[8];
    const int g = blockIdx.x;
    float* row = out + (size_t)g * NOUT;
    const int tid  = threadIdx.x;
    const int wid  = tid >> 6;
    const int lane = tid & 63;

    float v[4];
    float m = -INFINITY;
#pragma unroll
    for (int k = 0; k < 4; ++k) {
        const int j = tid + k * 256;
        v[k] = (j < NOUT) ? row[j] : -INFINITY;
        m = fmaxf(m, v[k]);
    }
#pragma unroll
    for (int off = 32; off > 0; off >>= 1) m = fmaxf(m, __shfl_xor(m, off));
    if (lane == 0) red[wid] = m;
    __syncthreads();
    m = fmaxf(fmaxf(red[0], red[1]), fmaxf(red[2], red[3]));

    float s = 0.f;
#pragma unroll
    for (int k = 0; k < 4; ++k) {
        const int j = tid + k * 256;
        if (j < NOUT) s += expf(v[k] - m);
    }
#pragma unroll
    for (int off = 32; off > 0; off >>= 1) s += __shfl_xor(s, off);
    if (lane == 0) red[4 + wid] = s;
    __syncthreads();
    s = red[4] + red[5] + red[6] + red[7];

    const float lse = m + logf(s);
#pragma unroll
    for (int k = 0; k < 4; ++k) {
        const int j = tid + k * 256;
        if (j < NOUT) row[j] = v[k] - lse;
    }
}

// ---------------------------------------------------------------------------
extern "C" void kernel_launch(void* const* d_in, const int* in_sizes, int n_in,
                              void* d_out, int out_size, void* d_ws, size_t ws_size,
                              hipStream_t stream)
{
    // setup_inputs() dict order
    const int*   gidx  = (const int*)  d_in[0];   // global_idx  [N]
    const float* acts  = (const float*)d_in[1];   // acts        [N,2]
    const int*   batch = (const int*)  d_in[4];   // batch       [N] (sorted)
    const float* emb   = (const float*)d_in[5];   // emb_weight  [20000,256]
    const float* peW   = (const float*)d_in[6];   // pe_W        [2,256]
    const float* peb   = (const float*)d_in[7];   // pe_b        [256]
    const float* fc1W  = (const float*)d_in[19];  // fc1_W       [256,512]
    const float* fc1b  = (const float*)d_in[20];  // fc1_b       [512]
    const float* fc2W  = (const float*)d_in[21];  // fc2_W       [512,978]
    const float* fc2b  = (const float*)d_in[22];  // fc2_b       [978]
    // d_in[2,3,8..18] (edge_index, sign, cg_*, gat_*, bn_*, prelu) are dead
    // code w.r.t. the reference output (it pools x, not h).

    float* partials = (float*)d_ws;                      // 256*256 f32 = 256 KB
    float* z        = partials + NGRAPHS * SUBS * DIM;   // 64*512 f32 = 128 KB
    // No zeroing kernel: partials/z/out are fully overwritten every call.

    pool_k<<<NGRAPHS * SUBS, 256, 0, stream>>>(gidx, acts, batch, emb, peW, peb, partials);
    fc1_k<<<dim3(2, NGRAPHS), 256, 0, stream>>>(partials, fc1W, fc1b, z);
    fc2_k<<<dim3(4, NGRAPHS / 4), 256, 0, stream>>>(z, fc2W, fc2b, (float*)d_out);
    lsm_k<<<NGRAPHS, 256, 0, stream>>>((float*)d_out);
}

// Round 7
// 62.808 us; speedup vs baseline: 1.5232x; 1.0159x over previous
//
#include <hip/hip_runtime.h>

// Live dataflow of the reference (everything else is dead code — the
// reference pools the INPUT features x, never h):
//   x[i]      = emb_weight[global_idx[i]] + acts[i] @ pe_W + pe_b      [N,256]
//   pooled[g] = sum_{batch[i]==g} x[i]                                 [64,256]
//   z         = relu(pooled @ fc1_W + fc1_b)                           [64,512]
//   out       = log_softmax(z @ fc2_W + fc2_b)                         [64,978]
//
// R6 post-mortem: totals across R3-R6 reconcile to (fixed ~41 µs harness
// workspace-poison fill) + (our kernels). pool_k is now ~12 µs. This round:
// double pool TLP (SUBS 8 -> 512 blocks, 2/CU) and halve the fc kernels'
// per-block L2 traffic (more, smaller col-tiles).

#define NNODES  100000
#define NGRAPHS 64
#define DIM     256
#define HID     512
#define NOUT    978
#define SUBS    8        // sub-blocks per graph; grid = 64*8 = 512 blocks
#define CHUNKS  32       // chunks per graph = SUBS * 4 waves

// ---------------------------------------------------------------------------
// Kernel 1: fused embed + pe-linear + segment-sum, atomic-free.
// Block b = (graph g = b/8, slice s = b%8). Range [lo,hi) via inline dual
// binary search on sorted batch (wave-uniform). Each of 4 waves sums a
// contiguous ~len/32 chunk (~49 rows; groups of 8 -> 24 outstanding loads),
// folds the pe term (sum-of-acts trick), LDS-reduces, writes ONE partials
// row per block with plain stores. 512 blocks = 2/CU = 8 waves/CU.
// ---------------------------------------------------------------------------
__global__ __launch_bounds__(256) void pool_k(
    const int* __restrict__ gidx, const float* __restrict__ acts,
    const int* __restrict__ batch, const float* __restrict__ emb,
    const float* __restrict__ peW, const float* __restrict__ peb,
    float* __restrict__ partials)
{
    const int b    = blockIdx.x;
    const int g    = b >> 3;
    const int s    = b & 7;
    const int w    = threadIdx.x >> 6;
    const int lane = threadIdx.x & 63;

    // dual lower_bound: lo = first i with batch[i] >= g, hi = ... >= g+1.
    // Two independent chains interleaved for ILP; 2^17 > 100000.
    int l0 = 0, r0 = NNODES, l1 = 0, r1 = NNODES;
#pragma unroll
    for (int it = 0; it < 17; ++it) {
        if (l0 < r0) { const int m = (l0 + r0) >> 1; if (batch[m] <  g)     l0 = m + 1; else r0 = m; }
        if (l1 < r1) { const int m = (l1 + r1) >> 1; if (batch[m] <  g + 1) l1 = m + 1; else r1 = m; }
    }
    const int lo = l0, hi = l1;

    const int cw    = s * 4 + w;                  // 0..31 chunk id within graph
    const int chunk = (hi - lo + CHUNKS - 1) >> 5;
    int       i     = lo + cw * chunk;
    const int iend  = min(i + chunk, hi);

    const float4 w0 = ((const float4*)peW)[lane];          // pe_W row 0 slice
    const float4 w1 = ((const float4*)(peW + DIM))[lane];  // pe_W row 1 slice
    const float4 pb = ((const float4*)peb)[lane];          // pe_b slice

    float4 acc = make_float4(0.f, 0.f, 0.f, 0.f);
    float  ax = 0.f, ay = 0.f, cnt = 0.f;

#define EROW(P) (*(const float4*)(emb + ((size_t)(P) << 8) + lane * 4))
#pragma unroll 2
    for (; i + 8 <= iend; i += 8) {
        // 8 independent index loads + 8 acts loads + 8 row gathers in flight
        const int j0 = gidx[i + 0], j1 = gidx[i + 1], j2 = gidx[i + 2], j3 = gidx[i + 3];
        const int j4 = gidx[i + 4], j5 = gidx[i + 5], j6 = gidx[i + 6], j7 = gidx[i + 7];
        const float2 a0 = ((const float2*)acts)[i + 0], a1 = ((const float2*)acts)[i + 1];
        const float2 a2 = ((const float2*)acts)[i + 2], a3 = ((const float2*)acts)[i + 3];
        const float2 a4 = ((const float2*)acts)[i + 4], a5 = ((const float2*)acts)[i + 5];
        const float2 a6 = ((const float2*)acts)[i + 6], a7 = ((const float2*)acts)[i + 7];
        const float4 e0 = EROW(j0), e1 = EROW(j1), e2 = EROW(j2), e3 = EROW(j3);
        const float4 e4 = EROW(j4), e5 = EROW(j5), e6 = EROW(j6), e7 = EROW(j7);

        acc.x += ((e0.x + e1.x) + (e2.x + e3.x)) + ((e4.x + e5.x) + (e6.x + e7.x));
        acc.y += ((e0.y + e1.y) + (e2.y + e3.y)) + ((e4.y + e5.y) + (e6.y + e7.y));
        acc.z += ((e0.z + e1.z) + (e2.z + e3.z)) + ((e4.z + e5.z) + (e6.z + e7.z));
        acc.w += ((e0.w + e1.w) + (e2.w + e3.w)) + ((e4.w + e5.w) + (e6.w + e7.w));
        ax    += ((a0.x + a1.x) + (a2.x + a3.x)) + ((a4.x + a5.x) + (a6.x + a7.x));
        ay    += ((a0.y + a1.y) + (a2.y + a3.y)) + ((a4.y + a5.y) + (a6.y + a7.y));
        cnt   += 8.f;
    }
    for (; i < iend; ++i) {                       // <=7 tail rows
        const int    j = gidx[i];
        const float2 a = ((const float2*)acts)[i];
        const float4 e = EROW(j);
        acc.x += e.x; acc.y += e.y; acc.z += e.z; acc.w += e.w;
        ax += a.x; ay += a.y; cnt += 1.f;
    }
#undef EROW

    // fold pe contribution: sum_i (acts_i @ pe_W + pe_b)
    acc.x += ax * w0.x + ay * w1.x + cnt * pb.x;
    acc.y += ax * w0.y + ay * w1.y + cnt * pb.y;
    acc.z += ax * w0.z + ay * w1.z + cnt * pb.z;
    acc.w += ax * w0.w + ay * w1.w + cnt * pb.w;

    // reduce the block's 4 waves in LDS; wave 0 writes the partials row
    __shared__ float4 red[4][64];
    red[w][lane] = acc;
    __syncthreads();
    if (w == 0) {
        const float4 r0_ = red[0][lane], r1_ = red[1][lane];
        const float4 r2_ = red[2][lane], r3_ = red[3][lane];
        float4 o;
        o.x = (r0_.x + r1_.x) + (r2_.x + r3_.x);
        o.y = (r0_.y + r1_.y) + (r2_.y + r3_.y);
        o.z = (r0_.z + r1_.z) + (r2_.z + r3_.z);
        o.w = (r0_.w + r1_.w) + (r2_.w + r3_.w);
        ((float4*)(partials + (size_t)b * DIM))[lane] = o;   // plain store
    }
}

// ---------------------------------------------------------------------------
// Kernel 2: z = relu(pooled @ fc1_W + fc1_b); pooled[g] = sum of the graph's
// SUBS partial rows (summed on the fly). Grid (4 col-tiles of 128, 64
// graphs), 128-thread blocks: 128 KB of W1 per block (~1 us per-CU L2 BW).
// ---------------------------------------------------------------------------
__global__ __launch_bounds__(128) void fc1_k(
    const float* __restrict__ partials, const float* __restrict__ W,
    const float* __restrict__ bias, float* __restrict__ z)
{
    __shared__ float xs[DIM];
    const int g = blockIdx.y;
    const int j = blockIdx.x * 128 + threadIdx.x;   // 0..511

    const float* pg = partials + (size_t)(g << 3) * DIM;
#pragma unroll
    for (int c = threadIdx.x; c < DIM; c += 128) {
        float v = 0.f;
#pragma unroll
        for (int s = 0; s < SUBS; ++s) v += pg[s * DIM + c];   // coalesced
        xs[c] = v;
    }
    __syncthreads();

    float acc = bias[j];
#pragma unroll 4
    for (int d = 0; d < DIM; d += 4) {
        const float4 x4 = *(const float4*)(xs + d);
        acc = fmaf(x4.x, W[(d + 0) * HID + j], acc);
        acc = fmaf(x4.y, W[(d + 1) * HID + j], acc);
        acc = fmaf(x4.z, W[(d + 2) * HID + j], acc);
        acc = fmaf(x4.w, W[(d + 3) * HID + j], acc);
    }
    z[g * HID + j] = fmaxf(acc, 0.f);
}

// ---------------------------------------------------------------------------
// Kernel 3a: logits = z @ fc2_W + fc2_b into d_out.  Grid (8 col-tiles of
// 128, 16 graph-quads), 128-thread blocks: 256 KB of W2 per block, each W
// column load feeds FOUR graphs' FMAs.
// ---------------------------------------------------------------------------
__global__ __launch_bounds__(128) void fc2_k(
    const float* __restrict__ z, const float* __restrict__ W,
    const float* __restrict__ bias, float* __restrict__ out)
{
    __shared__ float zs[4 * HID];
    const int g0 = blockIdx.y * 4;
    const int j = blockIdx.x * 128 + threadIdx.x;   // 0..1023
#pragma unroll
    for (int k = 0; k < 16; ++k) {
        const int idx = threadIdx.x + k * 128;      // 0..2047
        zs[idx] = z[g0 * HID + idx];                // rows g0..g0+3
    }
    __syncthreads();
    if (j >= NOUT) return;

    float acc0 = bias[j], acc1 = acc0, acc2 = acc0, acc3 = acc0;
#pragma unroll 2
    for (int d = 0; d < HID; d += 4) {
        const float4 za = *(const float4*)(zs + d);
        const float4 zb = *(const float4*)(zs + HID + d);
        const float4 zc = *(const float4*)(zs + 2 * HID + d);
        const float4 zd = *(const float4*)(zs + 3 * HID + d);
        const float wa = W[(d + 0) * NOUT + j];
        const float wb = W[(d + 1) * NOUT + j];
        const float wc = W[(d + 2) * NOUT + j];
        const float wd = W[(d + 3) * NOUT + j];
        acc0 = fmaf(za.x, wa, acc0); acc1 = fmaf(zb.x, wa, acc1);
        acc2 = fmaf(zc.x, wa, acc2); acc3 = fmaf(zd.x, wa, acc3);
        acc0 = fmaf(za.y, wb, acc0); acc1 = fmaf(zb.y, wb, acc1);
        acc2 = fmaf(zc.y, wb, acc2); acc3 = fmaf(zd.y, wb, acc3);
        acc0 = fmaf(za.z, wc, acc0); acc1 = fmaf(zb.z, wc, acc1);
        acc2 = fmaf(zc.z, wc, acc2); acc3 = fmaf(zd.z, wc, acc3);
        acc0 = fmaf(za.w, wd, acc0); acc1 = fmaf(zb.w, wd, acc1);
        acc2 = fmaf(zc.w, wd, acc2); acc3 = fmaf(zd.w, wd, acc3);
    }
    out[(size_t)(g0 + 0) * NOUT + j] = acc0;
    out[(size_t)(g0 + 1) * NOUT + j] = acc1;
    out[(size_t)(g0 + 2) * NOUT + j] = acc2;
    out[(size_t)(g0 + 3) * NOUT + j] = acc3;
}

// ---------------------------------------------------------------------------
// Kernel 3b: in-place row log-softmax.  One block (4 waves) per graph row.
// ---------------------------------------------------------------------------
__global__ __launch_bounds__(256) void lsm_k(float* __restrict__ out)
{
    __shared__ float red[8];
    const int g = blockIdx.x;
    float* row = out + (size_t)g * NOUT;
    const int tid  = threadIdx.x;
    const int wid  = tid >> 6;
    const int lane = tid & 63;

    float v[4];
    float m = -INFINITY;
#pragma unroll
    for (int k = 0; k < 4; ++k) {
        const int j = tid + k * 256;
        v[k] = (j < NOUT) ? row[j] : -INFINITY;
        m = fmaxf(m, v[k]);
    }
#pragma unroll
    for (int off = 32; off > 0; off >>= 1) m = fmaxf(m, __shfl_xor(m, off));
    if (lane == 0) red[wid] = m;
    __syncthreads();
    m = fmaxf(fmaxf(red[0], red[1]), fmaxf(red[2], red[3]));

    float s = 0.f;
#pragma unroll
    for (int k = 0; k < 4; ++k) {
        const int j = tid + k * 256;
        if (j < NOUT) s += expf(v[k] - m);
    }
#pragma unroll
    for (int off = 32; off > 0; off >>= 1) s += __shfl_xor(s, off);
    if (lane == 0) red[4 + wid] = s;
    __syncthreads();
    s = red[4] + red[5] + red[6] + red[7];

    const float lse = m + logf(s);
#pragma unroll
    for (int k = 0; k < 4; ++k) {
        const int j = tid + k * 256;
        if (j < NOUT) row[j] = v[k] - lse;
    }
}

// ---------------------------------------------------------------------------
extern "C" void kernel_launch(void* const* d_in, const int* in_sizes, int n_in,
                              void* d_out, int out_size, void* d_ws, size_t ws_size,
                              hipStream_t stream)
{
    // setup_inputs() dict order
    const int*   gidx  = (const int*)  d_in[0];   // global_idx  [N]
    const float* acts  = (const float*)d_in[1];   // acts        [N,2]
    const int*   batch = (const int*)  d_in[4];   // batch       [N] (sorted)
    const float* emb   = (const float*)d_in[5];   // emb_weight  [20000,256]
    const float* peW   = (const float*)d_in[6];   // pe_W        [2,256]
    const float* peb   = (const float*)d_in[7];   // pe_b        [256]
    const float* fc1W  = (const float*)d_in[19];  // fc1_W       [256,512]
    const float* fc1b  = (const float*)d_in[20];  // fc1_b       [512]
    const float* fc2W  = (const float*)d_in[21];  // fc2_W       [512,978]
    const float* fc2b  = (const float*)d_in[22];  // fc2_b       [978]
    // d_in[2,3,8..18] (edge_index, sign, cg_*, gat_*, bn_*, prelu) are dead
    // code w.r.t. the reference output (it pools x, not h).

    float* partials = (float*)d_ws;                      // 512*256 f32 = 512 KB
    float* z        = partials + NGRAPHS * SUBS * DIM;   // 64*512 f32 = 128 KB
    // No zeroing: partials/z/out are fully overwritten every call.

    pool_k<<<NGRAPHS * SUBS, 256, 0, stream>>>(gidx, acts, batch, emb, peW, peb, partials);
    fc1_k<<<dim3(4, NGRAPHS), 128, 0, stream>>>(partials, fc1W, fc1b, z);
    fc2_k<<<dim3(8, NGRAPHS / 4), 128, 0, stream>>>(z, fc2W, fc2b, (float*)d_out);
    lsm_k<<<NGRAPHS, 256, 0, stream>>>((float*)d_out);
}